// Round 6
// baseline (148.870 us; speedup 1.0000x reference)
//
#include <hip/hip_runtime.h>

#define BATCH 2
#define N 1024
#define NBINS 22
#define TDIM 16
#define TSTR 20   // padded LDS table row stride in floats: 80 B (16B-aligned rows)
#define SEGS 4    // quarter-rows per (batch,i) row -> 8192 blocks, 16 KB written each

typedef float nfloat4 __attribute__((ext_vector_type(4)));  // native vec for nontemporal builtin

__global__ __launch_bounds__(256) void te_enc(
    const float* __restrict__ coords,   // (B,N,3) f32
    const float* __restrict__ confp,    // (B,N)   f32
    const float* __restrict__ Wp,       // (22,16) f32
    const float* __restrict__ bp,       // (16)    f32
    const float* __restrict__ gp,       // (16)    f32
    const float* __restrict__ betap,    // (16)    f32
    float* __restrict__ out)            // (B,N,N,16) f32
{
    __shared__ __align__(16) float tbl[NBINS * TSTR];   // 1.76 KB
    __shared__ float4 ljc[N / SEGS];                    // 4 KB: (x,y,z,conf) per j in segment

    const int tid = threadIdx.x;
    const int blk = blockIdx.x;            // 0..8191
    const int batch = blk >> 12;           // /4096
    const int i   = (blk >> 2) & (N - 1);
    const int seg = blk & (SEGS - 1);

    const float* jc = coords + batch * N * 3;
    const float* jf = confp + batch * N;

    // Stage this segment's (x,y,z,conf): one j per thread.
    {
        const int j = seg * 256 + tid;
        float4 v;
        v.x = jc[j * 3 + 0];
        v.y = jc[j * 3 + 1];
        v.z = jc[j * 3 + 2];
        v.w = jf[j];
        ljc[tid] = v;
    }

    // Per-bin Linear+LayerNorm+ReLU rows (one thread per bin) — the one_hot @ W
    // MLP head collapses to a 22x16 table.
    if (tid < NBINS) {
        float h[TDIM];
        float sum = 0.f;
        #pragma unroll
        for (int d = 0; d < TDIM; ++d) {
            h[d] = Wp[tid * TDIM + d] + bp[d];
            sum += h[d];
        }
        const float mu = sum * (1.f / TDIM);
        float s2 = 0.f;
        #pragma unroll
        for (int d = 0; d < TDIM; ++d) {
            const float t = h[d] - mu;
            s2 += t * t;
        }
        const float rs = 1.f / sqrtf(s2 * (1.f / TDIM) + 1e-5f);
        #pragma unroll
        for (int d = 0; d < TDIM; ++d) {
            const float v = (h[d] - mu) * rs * gp[d] + betap[d];
            tbl[tid * TSTR + d] = fmaxf(v, 0.f);
        }
    }
    __syncthreads();

    const float xi = coords[(batch * N + i) * 3 + 0];
    const float yi = coords[(batch * N + i) * 3 + 1];
    const float zi = coords[(batch * N + i) * 3 + 2];
    const float ci = confp[batch * N + i];
    const bool ci_ok = (ci > 0.f);

    // Lane-major coalesced stores: wave w covers 64 j's of this segment.
    // Store float4 index (in row space) = seg*1024 + w*256 + 64*c + l;
    // j_local = w*64 + 16*c + (l>>2), sub = l&3 (4-lane-redundant bin calc).
    const int w   = tid >> 6;
    const int l   = tid & 63;
    const int lq  = l >> 2;
    const int sub = l & 3;

    nfloat4* orow4 = (nfloat4*)out + ((size_t)(batch * N + i)) * (N * TDIM / 4)
                   + seg * 1024 + w * 256;
    const float EW = (float)(40.0 / 21.0);   // same edge expression as np.arange f32

    #pragma unroll
    for (int c = 0; c < 4; ++c) {
        const int jl = w * 64 + 16 * c + lq;
        const float4 pj = ljc[jl];

        // Exact-f32 distance, numpy op order; *_rn blocks FMA contraction.
        const float dx = __fsub_rn(xi, pj.x);
        const float dy = __fsub_rn(yi, pj.y);
        const float dz = __fsub_rn(zi, pj.z);
        float s = __fmul_rn(dx, dx);
        s = __fadd_rn(s, __fmul_rn(dy, dy));
        s = __fadd_rn(s, __fmul_rn(dz, dz));
        s = __fadd_rn(s, 1e-8f);
        const float dist = __fsqrt_rn(s);

        // O(1) searchsorted(side='left'): trunc estimate + two exact boundary
        // compares against fl(k*EW) — identical to the 20-compare scan.
        int k0 = (int)__fmul_rn(dist, 0.525f);
        k0 = k0 < 20 ? k0 : 20;
        const int c1 = (__fmul_rn((float)k0, EW) < dist) ? 1 : 0;
        const int c2 = (__fmul_rn((float)(k0 + 1), EW) < dist) ? 1 : 0;
        const int idx = k0 + c1 + c2;
        int bin = idx < 20 ? idx : 20;                 // clip to NUM_BINS-2
        if (!(ci_ok && pj.w > 0.f)) bin = NBINS - 1;   // no-template bin
        const float cm = fminf(ci, pj.w);

        const float4 r = *(const float4*)&tbl[bin * TSTR + sub * 4];
        nfloat4 o;
        o.x = r.x * cm; o.y = r.y * cm; o.z = r.z * cm; o.w = r.w * cm;

        // Output is never re-read: nontemporal store skips L2 allocation.
        __builtin_nontemporal_store(o, &orow4[64 * c + l]);
    }
}

extern "C" void kernel_launch(void* const* d_in, const int* in_sizes, int n_in,
                              void* d_out, int out_size, void* d_ws, size_t ws_size,
                              hipStream_t stream) {
    const float* coords = (const float*)d_in[0];
    const float* conf   = (const float*)d_in[1];
    const float* W      = (const float*)d_in[2];
    const float* b      = (const float*)d_in[3];
    const float* g      = (const float*)d_in[4];
    const float* beta   = (const float*)d_in[5];
    float* out          = (float*)d_out;

    te_enc<<<dim3(BATCH * N * SEGS), dim3(256), 0, stream>>>(coords, conf, W, b, g, beta, out);
}